// Round 6
// baseline (126.169 us; speedup 1.0000x reference)
//
#include <hip/hip_runtime.h>
#include <cstdint>
#include <cstddef>

// ---------------------------------------------------------------------------
// MultiHeadAttention: B=2 T=2048 C=1024 H=16 D=64, fp32 in/out, bf16 compute.
// cvt(x) -> transpose-cvt(W*) -> QKV GEMM (m97-style, scale folded into Q)
// -> flash attention (swapped-QK 32x32 MFMA, in-register softmax, defer-max,
//    block-shared K/V LDS 3-buffer staged via global_load_lds with COUNTED
//    vmcnt + raw s_barrier (T3/T4), balanced CU pairing, setprio (T5))
// -> proj GEMM + bias.
// ---------------------------------------------------------------------------

typedef __bf16 bf16;
typedef __attribute__((ext_vector_type(2))) __bf16 bf16x2;
typedef __attribute__((ext_vector_type(4))) __bf16 bf16x4;
typedef __attribute__((ext_vector_type(8))) __bf16 bf16x8;
typedef __attribute__((ext_vector_type(4))) float f32x4;
typedef __attribute__((ext_vector_type(16))) float f32x16;
typedef __attribute__((ext_vector_type(4))) uint32_t u32x4;

#define AS1 __attribute__((address_space(1)))
#define AS3 __attribute__((address_space(3)))
typedef const AS1 void* gptr_t;
typedef AS3 void* lptr_t;

static constexpr int Bb = 2, Tt = 2048, Cc = 1024, Hh = 16, Dd = 64;
static constexpr int Mtot = Bb * Tt;   // 4096
static constexpr int Ktot = Cc;        // 1024
static constexpr int Ntot = Hh * Dd;   // 1024

// ---------------- fp32 -> bf16 elementwise convert -------------------------
__global__ void cvt_f32_bf16(const float* __restrict__ in, bf16* __restrict__ out, int n) {
  int i = (blockIdx.x * blockDim.x + threadIdx.x) * 4;
  if (i >= n) return;
  const float4 v = *reinterpret_cast<const float4*>(in + i);
  bf16x4 o;
  o[0] = (bf16)v.x; o[1] = (bf16)v.y; o[2] = (bf16)v.z; o[3] = (bf16)v.w;
  *reinterpret_cast<bf16x4*>(out + i) = o;
}

// ------------- batched [R][S] f32 -> [S][R] bf16 transpose -----------------
__global__ void transpose_cvt(const float* __restrict__ in, bf16* __restrict__ out,
                              int R, int S) {
  __shared__ float tile[32][33];
  const int batch = blockIdx.z;
  in  += (size_t)batch * R * S;
  out += (size_t)batch * R * S;
  const int r0 = blockIdx.y * 32, s0 = blockIdx.x * 32;
  const int tx = threadIdx.x, ty = threadIdx.y;   // 32 x 8
#pragma unroll
  for (int i = 0; i < 32; i += 8) {
    int r = r0 + ty + i, s = s0 + tx;
    tile[ty + i][tx] = (r < R && s < S) ? in[(size_t)r * S + s] : 0.f;
  }
  __syncthreads();
#pragma unroll
  for (int i = 0; i < 32; i += 8) {
    int s = s0 + ty + i, r = r0 + tx;
    if (s < S && r < R) out[(size_t)s * R + r] = (bf16)tile[tx][ty + i];
  }
}

// ---------------- 128x128 GEMM mainloop (m97 structure) --------------------
__device__ __forceinline__ void gemm_core_128(const bf16* __restrict__ A,
                                              const bf16* __restrict__ Bt,
                                              int m0, int n0, f32x4 acc[4][4]) {
  __shared__ __align__(16) char AsB[128 * 64 * 2];
  __shared__ __align__(16) char BsB[128 * 64 * 2];
  const int tid  = threadIdx.x;
  const int lane = tid & 63;
  const int w    = tid >> 6;
  const int li   = lane & 15, lg = lane >> 4;
  const int wr   = (w >> 1) * 64, wc = (w & 1) * 64;

  for (int kt = 0; kt < Ktot / 64; ++kt) {
    if (kt) __syncthreads();
#pragma unroll
    for (int it = 0; it < 4; ++it) {
      const int c   = it * 256 + tid;
      const int row = c >> 3, j = c & 7;
      const int jsw = j ^ (row & 7);
      const bf16* ga = A  + (size_t)(m0 + row) * Ktot + kt * 64 + jsw * 8;
      const bf16* gb = Bt + (size_t)(n0 + row) * Ktot + kt * 64 + jsw * 8;
      __builtin_amdgcn_global_load_lds(gptr_t(ga), lptr_t(AsB + (it * 256 + w * 64) * 16), 16, 0, 0);
      __builtin_amdgcn_global_load_lds(gptr_t(gb), lptr_t(BsB + (it * 256 + w * 64) * 16), 16, 0, 0);
    }
    __syncthreads();
#pragma unroll
    for (int kk = 0; kk < 2; ++kk) {
      bf16x8 af[4], bfv[4];
#pragma unroll
      for (int mi = 0; mi < 4; ++mi) {
        const int row = wr + mi * 16 + li;
        const int jj  = (kk * 4 + lg) ^ (row & 7);
        af[mi] = *reinterpret_cast<const bf16x8*>(AsB + row * 128 + jj * 16);
      }
#pragma unroll
      for (int ni = 0; ni < 4; ++ni) {
        const int row = wc + ni * 16 + li;
        const int jj  = (kk * 4 + lg) ^ (row & 7);
        bfv[ni] = *reinterpret_cast<const bf16x8*>(BsB + row * 128 + jj * 16);
      }
#pragma unroll
      for (int mi = 0; mi < 4; ++mi)
#pragma unroll
        for (int ni = 0; ni < 4; ++ni)
          acc[mi][ni] = __builtin_amdgcn_mfma_f32_16x16x32_bf16(af[mi], bfv[ni], acc[mi][ni], 0, 0, 0);
    }
  }
}

// ---------------- QKV projection GEMM --------------------------------------
// z=0 -> q [B,H,T,D] scaled by 1/sqrt(D)*log2(e); z=1 -> k; z=2 -> v^T [B,H,D,T]
__global__ __launch_bounds__(256) void qkv_gemm(const bf16* __restrict__ xb,
    const bf16* __restrict__ wqt, const bf16* __restrict__ wkt, const bf16* __restrict__ wvt,
    bf16* __restrict__ q, bf16* __restrict__ k, bf16* __restrict__ vt) {
  const int m0 = blockIdx.y * 128, n0 = blockIdx.x * 128;
  const int z  = blockIdx.z;
  const bf16* Bt = (z == 0) ? wqt : (z == 1) ? wkt : wvt;
  bf16* outp     = (z == 0) ? q   : (z == 1) ? k   : vt;
  const float scl = (z == 0) ? 0.18033688011112042f : 1.0f;  // (1/8)*log2(e)

  f32x4 acc[4][4];
#pragma unroll
  for (int mi = 0; mi < 4; ++mi)
#pragma unroll
    for (int ni = 0; ni < 4; ++ni) acc[mi][ni] = f32x4{0.f, 0.f, 0.f, 0.f};

  gemm_core_128(xb, Bt, m0, n0, acc);

  const int lane = threadIdx.x & 63, w = threadIdx.x >> 6;
  const int li = lane & 15, lg = lane >> 4;
  const int wr = (w >> 1) * 64, wc = (w & 1) * 64;
#pragma unroll
  for (int mi = 0; mi < 4; ++mi)
#pragma unroll
    for (int ni = 0; ni < 4; ++ni)
#pragma unroll
      for (int r = 0; r < 4; ++r) {
        const int mm = m0 + wr + mi * 16 + lg * 4 + r;   // b*T + t
        const int nn = n0 + wc + ni * 16 + li;           // h*64 + d
        const int b = mm >> 11, tt = mm & 2047;
        const int hd = nn >> 6, d = nn & 63;
        const float v = acc[mi][ni][r] * scl;
        if (z < 2) outp[(((size_t)(b * Hh + hd)) * Tt + tt) * Dd + d] = (bf16)v;
        else       outp[(((size_t)(b * Hh + hd)) * Dd + d) * Tt + tt] = (bf16)v;
      }
}

// ---------------- output projection GEMM (+bias, f32 out) ------------------
__global__ __launch_bounds__(256) void proj_gemm(const bf16* __restrict__ attnb,
    const bf16* __restrict__ wpt, float* __restrict__ out, const float* __restrict__ bias) {
  const int m0 = blockIdx.y * 128, n0 = blockIdx.x * 128;
  f32x4 acc[4][4];
#pragma unroll
  for (int mi = 0; mi < 4; ++mi)
#pragma unroll
    for (int ni = 0; ni < 4; ++ni) acc[mi][ni] = f32x4{0.f, 0.f, 0.f, 0.f};

  gemm_core_128(attnb, wpt, m0, n0, acc);

  const int lane = threadIdx.x & 63, w = threadIdx.x >> 6;
  const int li = lane & 15, lg = lane >> 4;
  const int wr = (w >> 1) * 64, wc = (w & 1) * 64;
#pragma unroll
  for (int mi = 0; mi < 4; ++mi)
#pragma unroll
    for (int ni = 0; ni < 4; ++ni)
#pragma unroll
      for (int r = 0; r < 4; ++r) {
        const int mm = m0 + wr + mi * 16 + lg * 4 + r;
        const int nn = n0 + wc + ni * 16 + li;
        out[(size_t)mm * Ntot + nn] = acc[mi][ni][r] + bias[nn];
      }
}

// ---------------- flash attention ------------------------------------------
__device__ __forceinline__ uint32_t pk(float a, float b) {
  bf16x2 t; t[0] = (bf16)a; t[1] = (bf16)b;
  return __builtin_bit_cast(uint32_t, t);
}
__device__ __forceinline__ bf16x8 mk8(uint32_t w0, uint32_t w1, uint32_t w2, uint32_t w3) {
  u32x4 u = {w0, w1, w2, w3};
  return __builtin_bit_cast(bf16x8, u);
}

// One BLOCK per (bh, 128-row q-tile); 4 waves x 32 q-rows, all waves walk the
// SAME 64-wide s-steps. K/V staged into a 3-buffer LDS rotation via
// global_load_lds; main loop uses COUNTED s_waitcnt vmcnt(4) + raw s_barrier
// (T3/T4) so prefetched loads stay in flight across barriers — never a full
// drain. Balanced CU pairing: block i (<256, jt=15..8 heavy) shares a CU with
// block i+256 (jt=0..7 light) -> per-CU work ~constant (34 block-steps).
__global__ __launch_bounds__(256, 2) void attn_kernel(const bf16* __restrict__ Q,
    const bf16* __restrict__ K, const bf16* __restrict__ Vt, bf16* __restrict__ O) {
  const int tid = threadIdx.x, lane = tid & 63, w = tid >> 6;
  const int x = lane & 31, h = lane >> 5;
  const int i    = (int)blockIdx.x;
  const int slot = i & 255;
  const int k8   = slot >> 5;                 // 0..7
  const int jt   = (i < 256) ? (15 - k8) : k8; // heavy half / light half
  const int bh   = slot & 31;                  // low bits -> XCD pinning per bh
  const int qr0 = jt * 128 + w * 32;      // this wave's 32 q-rows
  const int b = bh >> 4, hh = bh & 15;
  const int NSb     = 2 * jt + 2;         // block's 64-wide s-steps
  const int last_st = qr0 >> 6;           // this wave's diagonal step

  const bf16* Qh = Q  + (size_t)bh * Tt * Dd;
  const bf16* Kh = K  + (size_t)bh * Tt * Dd;
  const bf16* Vh = Vt + (size_t)bh * Dd * Tt;

  __shared__ __align__(16) char Kl[3][8192];   // 64 s-rows x 64 d (bf16)
  __shared__ __align__(16) char Vl[3][8192];   // 64 d-rows x 64 s (bf16)
  __shared__ float bc[4][32];                  // per-wave row broadcast

  // stage K/V tile for step st into buffer buf (linear LDS dest,
  // pre-swizzled global source; read side applies the same XOR).
  // 4 global_load_lds per thread per call (vmcnt accounting relies on this).
  auto STAGE = [&](int st, int buf) {
    const int s0 = st * 64;
#pragma unroll
    for (int rr = 0; rr < 2; ++rr) {
      const int c = rr * 256 + tid;          // chunk 0..511 (16B each)
      const int r = c >> 3, j = c & 7, jsw = j ^ (r & 7);
      __builtin_amdgcn_global_load_lds(gptr_t(Kh + (size_t)(s0 + r) * Dd + jsw * 8),
                                       lptr_t(Kl[buf] + c * 16), 16, 0, 0);
    }
#pragma unroll
    for (int rr = 0; rr < 2; ++rr) {
      const int c = rr * 256 + tid;
      const int r = c >> 3, j = c & 7, jsw = j ^ (r & 7);
      __builtin_amdgcn_global_load_lds(gptr_t(Vh + (size_t)r * Tt + s0 + jsw * 8),
                                       lptr_t(Vl[buf] + c * 16), 16, 0, 0);
    }
  };

  // Q B-frags (scale pre-folded at projection), resident all steps
  bf16x8 qf[4];
#pragma unroll
  for (int ks = 0; ks < 4; ++ks)
    qf[ks] = *reinterpret_cast<const bf16x8*>(Qh + (size_t)(qr0 + x) * Dd + ks * 16 + h * 8);

  f32x16 oc[2];
#pragma unroll
  for (int ns = 0; ns < 2; ++ns)
#pragma unroll
    for (int c = 0; c < 16; ++c) oc[ns][c] = 0.f;
  float m = -1e30f, l = 0.f;

  // prologue: stage tiles 0 and 1; wait tile0 (allow tile1 in flight)
  STAGE(0, 0);
  STAGE(1, 1);
  asm volatile("s_waitcnt vmcnt(4)" ::: "memory");
  __builtin_amdgcn_sched_barrier(0);
  __builtin_amdgcn_s_barrier();
  __builtin_amdgcn_sched_barrier(0);

  int cur = 0;
  for (int st = 0; st < NSb; ++st) {
    const bool pf = (st + 2 < NSb);
    if (pf) {
      int buf = cur + 2; if (buf >= 3) buf -= 3;
      STAGE(st + 2, buf);                      // stays in flight across this step
    }

    const int s0 = st * 64;
    if (st <= last_st) {                       // causally active for this wave
      // K A-frags from LDS (swizzled read)
      bf16x8 kf[2][4];
#pragma unroll
      for (int t = 0; t < 2; ++t)
#pragma unroll
        for (int ks = 0; ks < 4; ++ks) {
          const int row = 32 * t + x;
          const int cp  = (2 * ks + h) ^ (row & 7);
          kf[t][ks] = *reinterpret_cast<const bf16x8*>(Kl[cur] + (row * 8 + cp) * 16);
        }

      // S^T = K x Q^T  (log2 domain)
      f32x16 p[2];
      __builtin_amdgcn_s_setprio(1);
#pragma unroll
      for (int t = 0; t < 2; ++t) {
#pragma unroll
        for (int c = 0; c < 16; ++c) p[t][c] = 0.f;
#pragma unroll
        for (int ks = 0; ks < 4; ++ks)
          p[t] = __builtin_amdgcn_mfma_f32_32x32x16_bf16(kf[t][ks], qf[ks], p[t], 0, 0, 0);
      }
      __builtin_amdgcn_s_setprio(0);

      if (st == last_st) {                      // diagonal: causal mask
#pragma unroll
        for (int t = 0; t < 2; ++t)
#pragma unroll
          for (int c = 0; c < 16; ++c) {
            const int s = s0 + 32 * t + (c & 3) + 8 * (c >> 2) + 4 * h;
            if (s > qr0 + x) p[t][c] = -1e30f;
          }
      }

      // in-register row max (tree) + one cross-half shfl
      float mx[16];
#pragma unroll
      for (int ii = 0; ii < 16; ++ii) mx[ii] = fmaxf(p[0][ii], p[1][ii]);
#pragma unroll
      for (int srd = 8; srd >= 1; srd >>= 1)
#pragma unroll
        for (int ii = 0; ii < srd; ++ii) mx[ii] = fmaxf(mx[ii], mx[ii + srd]);
      const float pmax = fmaxf(mx[0], __shfl_xor(mx[0], 32, 64));

      // defer-max (T13): rescale O only when max grew by > 8 (log2 domain)
      if (!__all(pmax - m <= 8.f)) {
        const float mn  = fmaxf(m, pmax);
        const float fac = __builtin_amdgcn_exp2f(m - mn);
        l *= fac; m = mn;
        if (h == 0) bc[w][x] = fac;
#pragma unroll
        for (int c = 0; c < 16; ++c) {
          const float fr = bc[w][(c & 3) + 8 * (c >> 2) + 4 * h];
          oc[0][c] *= fr; oc[1][c] *= fr;
        }
      }

      // P = exp2(S - m); row sum (tree) + one cross-half shfl
#pragma unroll
      for (int t = 0; t < 2; ++t)
#pragma unroll
        for (int c = 0; c < 16; ++c) p[t][c] = __builtin_amdgcn_exp2f(p[t][c] - m);

      float sm[16];
#pragma unroll
      for (int ii = 0; ii < 16; ++ii) sm[ii] = p[0][ii] + p[1][ii];
#pragma unroll
      for (int srd = 8; srd >= 1; srd >>= 1)
#pragma unroll
        for (int ii = 0; ii < srd; ++ii) sm[ii] += sm[ii + srd];
      l += sm[0] + __shfl_xor(sm[0], 32, 64);

      // pack P to bf16 A-frags: 16 packs + 8 cross-half shfl + selects
      bf16x8 pa[4];
#pragma unroll
      for (int t = 0; t < 2; ++t) {
        uint32_t dw[8];
#pragma unroll
        for (int ii = 0; ii < 8; ++ii) dw[ii] = pk(p[t][2 * ii], p[t][2 * ii + 1]);
        const uint32_t rA = (uint32_t)__shfl_xor((int)(h ? dw[0] : dw[2]), 32, 64);
        const uint32_t rB = (uint32_t)__shfl_xor((int)(h ? dw[1] : dw[3]), 32, 64);
        const uint32_t rC = (uint32_t)__shfl_xor((int)(h ? dw[4] : dw[6]), 32, 64);
        const uint32_t rD = (uint32_t)__shfl_xor((int)(h ? dw[5] : dw[7]), 32, 64);
        pa[2 * t]     = mk8(h ? rA : dw[0], h ? rB : dw[1], h ? dw[2] : rA, h ? dw[3] : rB);
        pa[2 * t + 1] = mk8(h ? rC : dw[4], h ? rD : dw[5], h ? dw[6] : rC, h ? dw[7] : rD);
      }

      // V B-frags from LDS (swizzled read), then O += P x V
      bf16x8 vf[2][4];
#pragma unroll
      for (int ns = 0; ns < 2; ++ns)
#pragma unroll
        for (int ks = 0; ks < 4; ++ks) {
          const int row = ns * 32 + x;
          const int cp  = (2 * ks + h) ^ (row & 7);
          vf[ns][ks] = *reinterpret_cast<const bf16x8*>(Vl[cur] + (row * 8 + cp) * 16);
        }
      __builtin_amdgcn_s_setprio(1);
#pragma unroll
      for (int ns = 0; ns < 2; ++ns)
#pragma unroll
        for (int ks = 0; ks < 4; ++ks)
          oc[ns] = __builtin_amdgcn_mfma_f32_32x32x16_bf16(pa[ks], vf[ns][ks], oc[ns], 0, 0, 0);
      __builtin_amdgcn_s_setprio(0);
    }

    if (st + 1 < NSb) {
      // counted wait: tile st+1 must be landed; tile st+2 (4 loads) may fly
      if (pf) { asm volatile("s_waitcnt vmcnt(4)" ::: "memory"); }
      else    { asm volatile("s_waitcnt vmcnt(0)" ::: "memory"); }
      __builtin_amdgcn_sched_barrier(0);
      __builtin_amdgcn_s_barrier();
      __builtin_amdgcn_sched_barrier(0);
    }
    cur = (cur == 2) ? 0 : cur + 1;
  }

  // epilogue: O[q][d] / l[q]  (broadcast 1/l via LDS within the wave)
  if (h == 0) bc[w][x] = 1.f / l;
#pragma unroll
  for (int c = 0; c < 16; ++c) {
    const int q = (c & 3) + 8 * (c >> 2) + 4 * h;
    const float inv = bc[w][q];
    const int trow = qr0 + q;
#pragma unroll
    for (int ns = 0; ns < 2; ++ns)
      O[((size_t)b * Tt + trow) * Cc + hh * Dd + ns * 32 + x] = (bf16)(oc[ns][c] * inv);
  }
}

// ---------------------------------------------------------------------------
extern "C" void kernel_launch(void* const* d_in, const int* in_sizes, int n_in,
                              void* d_out, int out_size, void* d_ws, size_t ws_size,
                              hipStream_t stream) {
  const float* x  = (const float*)d_in[0];
  const float* Wq = (const float*)d_in[1];
  const float* Wk = (const float*)d_in[2];
  const float* Wv = (const float*)d_in[3];
  const float* Wp = (const float*)d_in[4];
  const float* bp = (const float*)d_in[5];
  float* out = (float*)d_out;

  char* ws = (char*)d_ws;
  size_t off = 0;
  auto grab = [&](size_t bytes) { char* p = ws + off; off += (bytes + 255) & ~(size_t)255; return p; };

  bf16* xb    = (bf16*)grab((size_t)Mtot * Ktot * 2);
  bf16* wqt   = (bf16*)grab((size_t)Ntot * Ktot * 2);
  bf16* wkt   = (bf16*)grab((size_t)Ntot * Ktot * 2);
  bf16* wvt   = (bf16*)grab((size_t)Ntot * Ktot * 2);
  bf16* wpt   = (bf16*)grab((size_t)Ntot * Ktot * 2);
  bf16* qb    = (bf16*)grab((size_t)Bb * Hh * Tt * Dd * 2);  // [B,H,T,D]
  bf16* kb    = (bf16*)grab((size_t)Bb * Hh * Tt * Dd * 2);
  bf16* vtb   = (bf16*)grab((size_t)Bb * Hh * Dd * Tt * 2);  // [B,H,D,T]
  bf16* attnb = (bf16*)grab((size_t)Mtot * Ntot * 2);        // [B,T,H*D]
  (void)ws_size;

  const int nx = Mtot * Ktot;
  cvt_f32_bf16<<<nx / (256 * 4), 256, 0, stream>>>(x, xb, nx);

  transpose_cvt<<<dim3(2, 32, 16), dim3(32, 8), 0, stream>>>(Wq, wqt, Cc, Dd);
  transpose_cvt<<<dim3(2, 32, 16), dim3(32, 8), 0, stream>>>(Wk, wkt, Cc, Dd);
  transpose_cvt<<<dim3(2, 32, 16), dim3(32, 8), 0, stream>>>(Wv, wvt, Cc, Dd);
  transpose_cvt<<<dim3(32, 32, 1), dim3(32, 8), 0, stream>>>(Wp, wpt, Ntot, Cc);

  qkv_gemm<<<dim3(Ntot / 128, Mtot / 128, 3), 256, 0, stream>>>(xb, wqt, wkt, wvt, qb, kb, vtb);
  attn_kernel<<<dim3(512), 256, 0, stream>>>(qb, kb, vtb, attnb);
  proj_gemm<<<dim3(Ntot / 128, Mtot / 128), 256, 0, stream>>>(attnb, wpt, out, bp);
}

// Round 7
// 116.440 us; speedup vs baseline: 1.0835x; 1.0835x over previous
//
#include <hip/hip_runtime.h>
#include <cstdint>
#include <cstddef>

// ---------------------------------------------------------------------------
// MultiHeadAttention: B=2 T=2048 C=1024 H=16 D=64, fp32 in/out, bf16 compute.
// cvt(x) -> transpose-cvt(W*) -> QKV GEMM (m97-style, scale folded into Q)
// -> flash attention: 8-wave blocks = 4 q-waves x 2 s-groups (split-s for
//    4 waves/SIMD TLP), shared LDS K/V double-buffer per group, swapped-QK
//    32x32 MFMA, in-register softmax, defer-max, 2-way LDS merge
// -> proj GEMM + bias.
// ---------------------------------------------------------------------------

typedef __bf16 bf16;
typedef __attribute__((ext_vector_type(2))) __bf16 bf16x2;
typedef __attribute__((ext_vector_type(4))) __bf16 bf16x4;
typedef __attribute__((ext_vector_type(8))) __bf16 bf16x8;
typedef __attribute__((ext_vector_type(4))) float f32x4;
typedef __attribute__((ext_vector_type(16))) float f32x16;
typedef __attribute__((ext_vector_type(4))) uint32_t u32x4;

#define AS1 __attribute__((address_space(1)))
#define AS3 __attribute__((address_space(3)))
typedef const AS1 void* gptr_t;
typedef AS3 void* lptr_t;

static constexpr int Bb = 2, Tt = 2048, Cc = 1024, Hh = 16, Dd = 64;
static constexpr int Mtot = Bb * Tt;   // 4096
static constexpr int Ktot = Cc;        // 1024
static constexpr int Ntot = Hh * Dd;   // 1024

// ---------------- fp32 -> bf16 elementwise convert -------------------------
__global__ void cvt_f32_bf16(const float* __restrict__ in, bf16* __restrict__ out, int n) {
  int i = (blockIdx.x * blockDim.x + threadIdx.x) * 4;
  if (i >= n) return;
  const float4 v = *reinterpret_cast<const float4*>(in + i);
  bf16x4 o;
  o[0] = (bf16)v.x; o[1] = (bf16)v.y; o[2] = (bf16)v.z; o[3] = (bf16)v.w;
  *reinterpret_cast<bf16x4*>(out + i) = o;
}

// ------------- batched [R][S] f32 -> [S][R] bf16 transpose -----------------
__global__ void transpose_cvt(const float* __restrict__ in, bf16* __restrict__ out,
                              int R, int S) {
  __shared__ float tile[32][33];
  const int batch = blockIdx.z;
  in  += (size_t)batch * R * S;
  out += (size_t)batch * R * S;
  const int r0 = blockIdx.y * 32, s0 = blockIdx.x * 32;
  const int tx = threadIdx.x, ty = threadIdx.y;   // 32 x 8
#pragma unroll
  for (int i = 0; i < 32; i += 8) {
    int r = r0 + ty + i, s = s0 + tx;
    tile[ty + i][tx] = (r < R && s < S) ? in[(size_t)r * S + s] : 0.f;
  }
  __syncthreads();
#pragma unroll
  for (int i = 0; i < 32; i += 8) {
    int s = s0 + ty + i, r = r0 + tx;
    if (s < S && r < R) out[(size_t)s * R + r] = (bf16)tile[tx][ty + i];
  }
}

// ---------------- 128x128 GEMM mainloop (m97 structure) --------------------
__device__ __forceinline__ void gemm_core_128(const bf16* __restrict__ A,
                                              const bf16* __restrict__ Bt,
                                              int m0, int n0, f32x4 acc[4][4]) {
  __shared__ __align__(16) char AsB[128 * 64 * 2];
  __shared__ __align__(16) char BsB[128 * 64 * 2];
  const int tid  = threadIdx.x;
  const int lane = tid & 63;
  const int w    = tid >> 6;
  const int li   = lane & 15, lg = lane >> 4;
  const int wr   = (w >> 1) * 64, wc = (w & 1) * 64;

  for (int kt = 0; kt < Ktot / 64; ++kt) {
    if (kt) __syncthreads();
#pragma unroll
    for (int it = 0; it < 4; ++it) {
      const int c   = it * 256 + tid;
      const int row = c >> 3, j = c & 7;
      const int jsw = j ^ (row & 7);
      const bf16* ga = A  + (size_t)(m0 + row) * Ktot + kt * 64 + jsw * 8;
      const bf16* gb = Bt + (size_t)(n0 + row) * Ktot + kt * 64 + jsw * 8;
      __builtin_amdgcn_global_load_lds(gptr_t(ga), lptr_t(AsB + (it * 256 + w * 64) * 16), 16, 0, 0);
      __builtin_amdgcn_global_load_lds(gptr_t(gb), lptr_t(BsB + (it * 256 + w * 64) * 16), 16, 0, 0);
    }
    __syncthreads();
#pragma unroll
    for (int kk = 0; kk < 2; ++kk) {
      bf16x8 af[4], bfv[4];
#pragma unroll
      for (int mi = 0; mi < 4; ++mi) {
        const int row = wr + mi * 16 + li;
        const int jj  = (kk * 4 + lg) ^ (row & 7);
        af[mi] = *reinterpret_cast<const bf16x8*>(AsB + row * 128 + jj * 16);
      }
#pragma unroll
      for (int ni = 0; ni < 4; ++ni) {
        const int row = wc + ni * 16 + li;
        const int jj  = (kk * 4 + lg) ^ (row & 7);
        bfv[ni] = *reinterpret_cast<const bf16x8*>(BsB + row * 128 + jj * 16);
      }
#pragma unroll
      for (int mi = 0; mi < 4; ++mi)
#pragma unroll
        for (int ni = 0; ni < 4; ++ni)
          acc[mi][ni] = __builtin_amdgcn_mfma_f32_16x16x32_bf16(af[mi], bfv[ni], acc[mi][ni], 0, 0, 0);
    }
  }
}

// ---------------- QKV projection GEMM --------------------------------------
// z=0 -> q [B,H,T,D] scaled by 1/sqrt(D)*log2(e); z=1 -> k; z=2 -> v^T [B,H,D,T]
__global__ __launch_bounds__(256) void qkv_gemm(const bf16* __restrict__ xb,
    const bf16* __restrict__ wqt, const bf16* __restrict__ wkt, const bf16* __restrict__ wvt,
    bf16* __restrict__ q, bf16* __restrict__ k, bf16* __restrict__ vt) {
  const int m0 = blockIdx.y * 128, n0 = blockIdx.x * 128;
  const int z  = blockIdx.z;
  const bf16* Bt = (z == 0) ? wqt : (z == 1) ? wkt : wvt;
  bf16* outp     = (z == 0) ? q   : (z == 1) ? k   : vt;
  const float scl = (z == 0) ? 0.18033688011112042f : 1.0f;  // (1/8)*log2(e)

  f32x4 acc[4][4];
#pragma unroll
  for (int mi = 0; mi < 4; ++mi)
#pragma unroll
    for (int ni = 0; ni < 4; ++ni) acc[mi][ni] = f32x4{0.f, 0.f, 0.f, 0.f};

  gemm_core_128(xb, Bt, m0, n0, acc);

  const int lane = threadIdx.x & 63, w = threadIdx.x >> 6;
  const int li = lane & 15, lg = lane >> 4;
  const int wr = (w >> 1) * 64, wc = (w & 1) * 64;
#pragma unroll
  for (int mi = 0; mi < 4; ++mi)
#pragma unroll
    for (int ni = 0; ni < 4; ++ni)
#pragma unroll
      for (int r = 0; r < 4; ++r) {
        const int mm = m0 + wr + mi * 16 + lg * 4 + r;   // b*T + t
        const int nn = n0 + wc + ni * 16 + li;           // h*64 + d
        const int b = mm >> 11, tt = mm & 2047;
        const int hd = nn >> 6, d = nn & 63;
        const float v = acc[mi][ni][r] * scl;
        if (z < 2) outp[(((size_t)(b * Hh + hd)) * Tt + tt) * Dd + d] = (bf16)v;
        else       outp[(((size_t)(b * Hh + hd)) * Dd + d) * Tt + tt] = (bf16)v;
      }
}

// ---------------- output projection GEMM (+bias, f32 out) ------------------
__global__ __launch_bounds__(256) void proj_gemm(const bf16* __restrict__ attnb,
    const bf16* __restrict__ wpt, float* __restrict__ out, const float* __restrict__ bias) {
  const int m0 = blockIdx.y * 128, n0 = blockIdx.x * 128;
  f32x4 acc[4][4];
#pragma unroll
  for (int mi = 0; mi < 4; ++mi)
#pragma unroll
    for (int ni = 0; ni < 4; ++ni) acc[mi][ni] = f32x4{0.f, 0.f, 0.f, 0.f};

  gemm_core_128(attnb, wpt, m0, n0, acc);

  const int lane = threadIdx.x & 63, w = threadIdx.x >> 6;
  const int li = lane & 15, lg = lane >> 4;
  const int wr = (w >> 1) * 64, wc = (w & 1) * 64;
#pragma unroll
  for (int mi = 0; mi < 4; ++mi)
#pragma unroll
    for (int ni = 0; ni < 4; ++ni)
#pragma unroll
      for (int r = 0; r < 4; ++r) {
        const int mm = m0 + wr + mi * 16 + lg * 4 + r;
        const int nn = n0 + wc + ni * 16 + li;
        out[(size_t)mm * Ntot + nn] = acc[mi][ni][r] + bias[nn];
      }
}

// ---------------- flash attention ------------------------------------------
__device__ __forceinline__ uint32_t pk(float a, float b) {
  bf16x2 t; t[0] = (bf16)a; t[1] = (bf16)b;
  return __builtin_bit_cast(uint32_t, t);
}
__device__ __forceinline__ bf16x8 mk8(uint32_t w0, uint32_t w1, uint32_t w2, uint32_t w3) {
  u32x4 u = {w0, w1, w2, w3};
  return __builtin_bit_cast(bf16x8, u);
}

// Block = (bh, 128 q-rows), 512 threads = 8 waves = 4 q-waves x 2 s-groups.
// Group g handles s-tiles with parity g; both groups advance in lockstep
// supersteps (jt+1 each; NSb=2jt+2 even -> no group tail). K/V staged into
// 4 LDS buffers (per-group double-buffer) via global_load_lds. 2-way merge
// at the end overlaid on the dead staging LDS. 4096 waves -> 4 waves/SIMD.
__global__ __launch_bounds__(512, 4) void attn_kernel(const bf16* __restrict__ Q,
    const bf16* __restrict__ K, const bf16* __restrict__ Vt, bf16* __restrict__ O) {
  const int tid = threadIdx.x, lane = tid & 63, wid = tid >> 6;
  const int x = lane & 31, h = lane >> 5;
  const int qw = wid & 3, g = wid >> 2;        // q-wave, s-group
  const int i    = (int)blockIdx.x;
  const int slot = i & 255;
  const int k8   = slot >> 5;                  // 0..7
  const int jt   = (i < 256) ? (15 - k8) : k8; // heavy half / light half (CU pairing)
  const int bh   = slot & 31;                  // low bits -> per-bh XCD pinning
  const int qr0  = jt * 128 + qw * 32;         // this wave's 32 q-rows
  const int b = bh >> 4, hh = bh & 15;
  const int nss    = jt + 1;                   // supersteps (tiles per group)
  const int st_max = 2 * jt + (qw >> 1);       // this q-wave's diagonal tile

  const bf16* Qh = Q  + (size_t)bh * Tt * Dd;
  const bf16* Kh = K  + (size_t)bh * Tt * Dd;
  const bf16* Vh = Vt + (size_t)bh * Dd * Tt;

  // 4 staging buffers: [0..8K) = K-tile (64 s x 64 d), [8K..16K) = V-tile
  __shared__ __align__(16) char KV[4][16384];
  __shared__ float bc[8][32];                  // per-wave defer-max broadcast
  __shared__ float Msh[8][32], Lsh[8][32], Fsh[8][32], Linv[4][32];

  // stage K+V tile st into buffer buf: 512 threads x 1 chunk each per half.
  // Linear LDS dest + pre-swizzled global source (G21); reads apply same XOR.
  auto STAGE = [&](int st, int buf) {
    const int s0 = st * 64;
    const int c = tid;                          // 0..511 (16B chunks)
    const int r = c >> 3, j = c & 7, jsw = j ^ (r & 7);
    __builtin_amdgcn_global_load_lds(gptr_t(Kh + (size_t)(s0 + r) * Dd + jsw * 8),
                                     lptr_t(KV[buf] + c * 16), 16, 0, 0);
    __builtin_amdgcn_global_load_lds(gptr_t(Vh + (size_t)r * Tt + s0 + jsw * 8),
                                     lptr_t(KV[buf] + 8192 + c * 16), 16, 0, 0);
  };

  // Q B-frags (scale pre-folded at projection), resident all steps
  bf16x8 qf[4];
#pragma unroll
  for (int ks = 0; ks < 4; ++ks)
    qf[ks] = *reinterpret_cast<const bf16x8*>(Qh + (size_t)(qr0 + x) * Dd + ks * 16 + h * 8);

  f32x16 oc[2];
#pragma unroll
  for (int ns = 0; ns < 2; ++ns)
#pragma unroll
    for (int c = 0; c < 16; ++c) oc[ns][c] = 0.f;
  float m = -1e30f, l = 0.f;

  // prologue: superstep-0 tiles for both groups
  STAGE(0, 0);       // group A tile 0
  STAGE(1, 2);       // group B tile 1
  __syncthreads();

  for (int ss = 0; ss < nss; ++ss) {
    const int par = ss & 1;
    if (ss + 1 < nss) {                        // prefetch next superstep's pair
      STAGE(2 * (ss + 1),     par ^ 1);        // group A next -> other A buf
      STAGE(2 * (ss + 1) + 1, 2 + (par ^ 1));  // group B next -> other B buf
    }

    const int st = g + 2 * ss;                 // this wave's tile
    if (st <= st_max) {
      const int bufi = g * 2 + par;
      const int s0 = st * 64;

      // K A-frags from LDS (swizzled read)
      bf16x8 kf[2][4];
#pragma unroll
      for (int t = 0; t < 2; ++t)
#pragma unroll
        for (int ks = 0; ks < 4; ++ks) {
          const int row = 32 * t + x;
          const int cp  = (2 * ks + h) ^ (row & 7);
          kf[t][ks] = *reinterpret_cast<const bf16x8*>(KV[bufi] + (row * 8 + cp) * 16);
        }

      // S^T = K x Q^T  (log2 domain)
      f32x16 p[2];
      __builtin_amdgcn_s_setprio(1);
#pragma unroll
      for (int t = 0; t < 2; ++t) {
#pragma unroll
        for (int c = 0; c < 16; ++c) p[t][c] = 0.f;
#pragma unroll
        for (int ks = 0; ks < 4; ++ks)
          p[t] = __builtin_amdgcn_mfma_f32_32x32x16_bf16(kf[t][ks], qf[ks], p[t], 0, 0, 0);
      }
      __builtin_amdgcn_s_setprio(0);

      if (st == st_max) {                      // diagonal: causal mask
#pragma unroll
        for (int t = 0; t < 2; ++t)
#pragma unroll
          for (int c = 0; c < 16; ++c) {
            const int s = s0 + 32 * t + (c & 3) + 8 * (c >> 2) + 4 * h;
            if (s > qr0 + x) p[t][c] = -1e30f;
          }
      }

      // in-register row max (tree) + one cross-half shfl
      float mx[16];
#pragma unroll
      for (int ii = 0; ii < 16; ++ii) mx[ii] = fmaxf(p[0][ii], p[1][ii]);
#pragma unroll
      for (int srd = 8; srd >= 1; srd >>= 1)
#pragma unroll
        for (int ii = 0; ii < srd; ++ii) mx[ii] = fmaxf(mx[ii], mx[ii + srd]);
      const float pmax = fmaxf(mx[0], __shfl_xor(mx[0], 32, 64));

      // defer-max (T13): rescale O only when max grew by > 8 (log2 domain)
      if (!__all(pmax - m <= 8.f)) {
        const float mn  = fmaxf(m, pmax);
        const float fac = __builtin_amdgcn_exp2f(m - mn);
        l *= fac; m = mn;
        if (h == 0) bc[wid][x] = fac;
#pragma unroll
        for (int c = 0; c < 16; ++c) {
          const float fr = bc[wid][(c & 3) + 8 * (c >> 2) + 4 * h];
          oc[0][c] *= fr; oc[1][c] *= fr;
        }
      }

      // P = exp2(S - m); row sum (tree) + one cross-half shfl
#pragma unroll
      for (int t = 0; t < 2; ++t)
#pragma unroll
        for (int c = 0; c < 16; ++c) p[t][c] = __builtin_amdgcn_exp2f(p[t][c] - m);

      float sm[16];
#pragma unroll
      for (int ii = 0; ii < 16; ++ii) sm[ii] = p[0][ii] + p[1][ii];
#pragma unroll
      for (int srd = 8; srd >= 1; srd >>= 1)
#pragma unroll
        for (int ii = 0; ii < srd; ++ii) sm[ii] += sm[ii + srd];
      l += sm[0] + __shfl_xor(sm[0], 32, 64);

      // pack P to bf16 A-frags: 16 packs + 8 cross-half shfl + selects
      bf16x8 pa[4];
#pragma unroll
      for (int t = 0; t < 2; ++t) {
        uint32_t dw[8];
#pragma unroll
        for (int ii = 0; ii < 8; ++ii) dw[ii] = pk(p[t][2 * ii], p[t][2 * ii + 1]);
        const uint32_t rA = (uint32_t)__shfl_xor((int)(h ? dw[0] : dw[2]), 32, 64);
        const uint32_t rB = (uint32_t)__shfl_xor((int)(h ? dw[1] : dw[3]), 32, 64);
        const uint32_t rC = (uint32_t)__shfl_xor((int)(h ? dw[4] : dw[6]), 32, 64);
        const uint32_t rD = (uint32_t)__shfl_xor((int)(h ? dw[5] : dw[7]), 32, 64);
        pa[2 * t]     = mk8(h ? rA : dw[0], h ? rB : dw[1], h ? dw[2] : rA, h ? dw[3] : rB);
        pa[2 * t + 1] = mk8(h ? rC : dw[4], h ? rD : dw[5], h ? dw[6] : rC, h ? dw[7] : rD);
      }

      // V B-frags from LDS (swizzled read), then O += P x V
      bf16x8 vf[2][4];
#pragma unroll
      for (int ns = 0; ns < 2; ++ns)
#pragma unroll
        for (int ks = 0; ks < 4; ++ks) {
          const int row = ns * 32 + x;
          const int cp  = (2 * ks + h) ^ (row & 7);
          vf[ns][ks] = *reinterpret_cast<const bf16x8*>(KV[bufi] + 8192 + (row * 8 + cp) * 16);
        }
      __builtin_amdgcn_s_setprio(1);
#pragma unroll
      for (int ns = 0; ns < 2; ++ns)
#pragma unroll
        for (int ks = 0; ks < 4; ++ks)
          oc[ns] = __builtin_amdgcn_mfma_f32_32x32x16_bf16(pa[ks], vf[ns][ks], oc[ns], 0, 0, 0);
      __builtin_amdgcn_s_setprio(0);
    }

    __syncthreads();   // next tiles landed + buffers safe to overwrite
  }

  // ---- 2-way flash-decoding merge (groups A,B per q-wave) ----
  if (h == 0) { Msh[wid][x] = m; Lsh[wid][x] = l; }
  __syncthreads();
  if (g == 0 && h == 0) {
    const float mA = Msh[qw][x], mB = Msh[4 + qw][x];
    const float ms = fmaxf(mA, mB);
    const float fA = __builtin_amdgcn_exp2f(mA - ms);
    const float fB = __builtin_amdgcn_exp2f(mB - ms);
    Fsh[qw][x] = fA; Fsh[4 + qw][x] = fB;
    Linv[qw][x] = 1.f / (Lsh[qw][x] * fA + Lsh[4 + qw][x] * fB);
  }
  __syncthreads();

  // partial-O accumulate in LDS overlaid on dead staging buffers.
  // OS[128][68] f32 (stride-68 pad -> <=4-way bank conflicts), 34.8KB.
  float (*OS)[68] = reinterpret_cast<float(*)[68]>(&KV[0][0]);
  if (g == 0) {
#pragma unroll
    for (int c = 0; c < 16; ++c) {
      const int row = (c & 3) + 8 * (c >> 2) + 4 * h;
      const float fr = Fsh[qw][row];
#pragma unroll
      for (int ns = 0; ns < 2; ++ns)
        OS[qw * 32 + row][ns * 32 + x] = oc[ns][c] * fr;
    }
  }
  __syncthreads();
  if (g == 1) {
#pragma unroll
    for (int c = 0; c < 16; ++c) {
      const int row = (c & 3) + 8 * (c >> 2) + 4 * h;
      const float fr = Fsh[4 + qw][row];
#pragma unroll
      for (int ns = 0; ns < 2; ++ns)
        OS[qw * 32 + row][ns * 32 + x] += oc[ns][c] * fr;
    }
  }
  __syncthreads();

  // store: 512 threads, each one (row, 16-d chunk) -> two bf16x8 writes
  {
    const int row = tid >> 2, d0 = (tid & 3) * 16;
    const float inv = Linv[row >> 5][row & 31];
    const int trow = jt * 128 + row;
    bf16x8 o1, o2;
#pragma unroll
    for (int ii = 0; ii < 8; ++ii) {
      o1[ii] = (bf16)(OS[row][d0 + ii] * inv);
      o2[ii] = (bf16)(OS[row][d0 + 8 + ii] * inv);
    }
    bf16* dst = &O[((size_t)b * Tt + trow) * Cc + hh * Dd + d0];
    *reinterpret_cast<bf16x8*>(dst)     = o1;
    *reinterpret_cast<bf16x8*>(dst + 8) = o2;
  }
}

// ---------------------------------------------------------------------------
extern "C" void kernel_launch(void* const* d_in, const int* in_sizes, int n_in,
                              void* d_out, int out_size, void* d_ws, size_t ws_size,
                              hipStream_t stream) {
  const float* x  = (const float*)d_in[0];
  const float* Wq = (const float*)d_in[1];
  const float* Wk = (const float*)d_in[2];
  const float* Wv = (const float*)d_in[3];
  const float* Wp = (const float*)d_in[4];
  const float* bp = (const float*)d_in[5];
  float* out = (float*)d_out;

  char* ws = (char*)d_ws;
  size_t off = 0;
  auto grab = [&](size_t bytes) { char* p = ws + off; off += (bytes + 255) & ~(size_t)255; return p; };

  bf16* xb    = (bf16*)grab((size_t)Mtot * Ktot * 2);
  bf16* wqt   = (bf16*)grab((size_t)Ntot * Ktot * 2);
  bf16* wkt   = (bf16*)grab((size_t)Ntot * Ktot * 2);
  bf16* wvt   = (bf16*)grab((size_t)Ntot * Ktot * 2);
  bf16* wpt   = (bf16*)grab((size_t)Ntot * Ktot * 2);
  bf16* qb    = (bf16*)grab((size_t)Bb * Hh * Tt * Dd * 2);  // [B,H,T,D]
  bf16* kb    = (bf16*)grab((size_t)Bb * Hh * Tt * Dd * 2);
  bf16* vtb   = (bf16*)grab((size_t)Bb * Hh * Dd * Tt * 2);  // [B,H,D,T]
  bf16* attnb = (bf16*)grab((size_t)Mtot * Ntot * 2);        // [B,T,H*D]
  (void)ws_size;

  const int nx = Mtot * Ktot;
  cvt_f32_bf16<<<nx / (256 * 4), 256, 0, stream>>>(x, xb, nx);

  transpose_cvt<<<dim3(2, 32, 16), dim3(32, 8), 0, stream>>>(Wq, wqt, Cc, Dd);
  transpose_cvt<<<dim3(2, 32, 16), dim3(32, 8), 0, stream>>>(Wk, wkt, Cc, Dd);
  transpose_cvt<<<dim3(2, 32, 16), dim3(32, 8), 0, stream>>>(Wv, wvt, Cc, Dd);
  transpose_cvt<<<dim3(32, 32, 1), dim3(32, 8), 0, stream>>>(Wp, wpt, Ntot, Cc);

  qkv_gemm<<<dim3(Ntot / 128, Mtot / 128, 3), 256, 0, stream>>>(xb, wqt, wkt, wvt, qb, kb, vtb);
  attn_kernel<<<dim3(512), 512, 0, stream>>>(qb, kb, vtb, attnb);
  proj_gemm<<<dim3(Ntot / 128, Mtot / 128), 256, 0, stream>>>(attnb, wpt, out, bp);
}